// Round 16
// baseline (300.718 us; speedup 1.0000x reference)
//
#include <hip/hip_runtime.h>
#include <hip/hip_bf16.h>

#define SLOPE 0.2f
#define NPB 64            // nodes per sort bucket
#define CAP 2048          // sortedSrc slots per bucket (mean 1638, 10 sigma)
#define SUBCAP 384        // pairW slots per (bucket, blockgroup) window
#define MAXBUCK 1024
#define EPB 16384         // edges per scatter chunk: runs ~21 words >= 1 full line
#define XF1B 512          // xform1 blocks (merged launch)
#define PPARTS 16         // pool partials per graph

typedef _Float16 f16x8  __attribute__((ext_vector_type(8)));
typedef float    f32x4  __attribute__((ext_vector_type(4)));
typedef unsigned u32;
typedef unsigned u32x4  __attribute__((ext_vector_type(4)));

__device__ __forceinline__ float lrelu(float v) { return fmaxf(v, SLOPE * v); }

__device__ __forceinline__ float lane_bcast(float v, int k) {
    return __int_as_float(__builtin_amdgcn_readlane(__float_as_int(v), k));
}

// packed f16 leaky-relu: max(v, 0.2*v) elementwise
__device__ __forceinline__ f16x8 lrelu8(f16x8 v) {
    f16x8 s = v * (_Float16)SLOPE;
#if __has_builtin(__builtin_elementwise_max)
    return __builtin_elementwise_max(v, s);
#else
    f16x8 r;
#pragma unroll
    for (int i = 0; i < 8; ++i) r[i] = v[i] > s[i] ? v[i] : s[i];
    return r;
#endif
}

// f32 -> (hi, lo) f16 split; hi+lo reproduces v to ~2^-22.
__device__ __forceinline__ void split_f16(float v, _Float16& h, _Float16& l) {
    h = (_Float16)v;
    l = (_Float16)(v - (float)h);
}
__device__ __forceinline__ u32 pack_f16(_Float16 a, _Float16 b) {
    return (u32)__builtin_bit_cast(unsigned short, a) |
           ((u32)__builtin_bit_cast(unsigned short, b) << 16);
}

// ---------------------------------------------------------------------------
// Merged launch: blocks [0,nCntB) counting-sort a 16384-edge chunk into
// 8-way sub-cursor bucket windows of pairW. Runs are ~21 words (>= 1 full
// 64B line), so pairW lines are single-writer -- no partial-line RMW or
// cross-XCD ownership migration. Blocks [nCntB,..): conv1 transform.
// ---------------------------------------------------------------------------
__global__ void __launch_bounds__(256) scatter_xform1_kernel(
    const int* __restrict__ srcI, const int* __restrict__ dstI,
    int* __restrict__ cursor, u32* __restrict__ pairW,
    int E, int nNodes, int nBuck, int nCntB,
    const float* __restrict__ x,
    const float* __restrict__ W1, const float* __restrict__ b1,
    _Float16* __restrict__ Ph, _Float16* __restrict__ Qh)
{
    if (blockIdx.x < nCntB) {
        __shared__ int cnt[MAXBUCK];
        __shared__ int base[MAXBUCK];
        const int tid = threadIdx.x;
        const int j   = blockIdx.x & 7;          // sub-cursor group (~XCD)
        const int e0 = blockIdx.x * EPB;
        const int e1 = min(e0 + EPB, E);

        for (int b = tid; b < nBuck; b += 256) cnt[b] = 0;
        __syncthreads();
        for (int e = e0 + tid; e < e1; e += 256)
            atomicAdd(&cnt[dstI[e] >> 6], 1);              // LDS atomic
        __syncthreads();
        for (int b = tid; b < nBuck; b += 256) {
            int c = cnt[b];
            base[b] = (c > 0)
                ? ((b * 8 + j) * SUBCAP + min(atomicAdd(&cursor[b * 8 + j], c), SUBCAP))
                : 0;
            cnt[b] = 0;
        }
        __syncthreads();
        for (int e = e0 + tid; e < e1; e += 256) {
            const int d = dstI[e];
            const int b = d >> 6;
            const int loc = atomicAdd(&cnt[b], 1);
            const int pos = min(base[b] + loc, (b * 8 + j + 1) * SUBCAP - 1);
            pairW[pos] = ((u32)srcI[e] << 6) | (u32)(d & (NPB - 1));
        }
        return;
    }
    const int lane = threadIdx.x & 63;
    const int wave = ((blockIdx.x - nCntB) * 256 + threadIdx.x) >> 6;
    const int nw   = (XF1B * 256) >> 6;

    float wd[6], wb[6];
#pragma unroll
    for (int r = 0; r < 6; ++r) {
        wb[r] = W1[(6 + r) * 64 + lane];
        wd[r] = W1[r * 64 + lane] - wb[r];
    }
    const float bb = b1[lane];
    for (int i = wave; i < nNodes; i += nw) {
        const float* xr = x + (size_t)i * 6;
        float p = bb, q = 0.f;
#pragma unroll
        for (int r = 0; r < 6; ++r) {
            float xv = xr[r];
            p = fmaf(xv, wd[r], p);
            q = fmaf(xv, wb[r], q);
        }
        Ph[(size_t)i * 64 + lane] = (_Float16)p;
        Qh[(size_t)i * 64 + lane] = (_Float16)q;
    }
}

// One block per bucket: count its 64 nodes from the 8 sub-windows (LDS),
// wave-prefix scan -> rowInfo (beg,len), then scatter sortedSrc.
__global__ void __launch_bounds__(256) bucket_sort_kernel(
    const u32* __restrict__ pairW, const int* __restrict__ cursor,
    int2* __restrict__ rowInfo, int* __restrict__ sortedSrc, int nNodes)
{
    __shared__ int nodeCnt[NPB];
    __shared__ int nodeCur[NPB];
    const int b   = blockIdx.x;
    const int n0  = b * NPB;
    const int n1  = min(n0 + NPB, nNodes);
    const int tid = threadIdx.x;
    if (tid < NPB) nodeCnt[tid] = 0;
    __syncthreads();
#pragma unroll
    for (int jj = 0; jj < 8; ++jj) {
        const int w0 = (b * 8 + jj) * SUBCAP;
        const int wc = min(cursor[b * 8 + jj], SUBCAP);
        for (int i = w0 + tid; i < w0 + wc; i += 256)
            atomicAdd(&nodeCnt[pairW[i] & (NPB - 1)], 1);
    }
    __syncthreads();
    if (tid < 64) {                       // wave 0: prefix scan of 64 counts
        const int c = nodeCnt[tid];
        int inc = c;
#pragma unroll
        for (int off = 1; off < 64; off <<= 1) {
            int t = __shfl_up(inc, off);
            if (tid >= off) inc += t;
        }
        const int st = b * CAP + inc - c; // exclusive, bucket-window-local
        nodeCur[tid] = st;
        if (tid < n1 - n0) rowInfo[n0 + tid] = make_int2(st, c);
    }
    __syncthreads();
#pragma unroll
    for (int jj = 0; jj < 8; ++jj) {
        const int w0 = (b * 8 + jj) * SUBCAP;
        const int wc = min(cursor[b * 8 + jj], SUBCAP);
        for (int i = w0 + tid; i < w0 + wc; i += 256) {
            const u32 w = pairW[i];
            const int pos = atomicAdd(&nodeCur[w & (NPB - 1)], 1);
            sortedSrc[pos] = (int)(w >> 6);
        }
    }
}

// ---------------------------------------------------------------------------
// Node transform for conv2 (f16 in/out, VALU readlane -- R13-proven):
//   P[i] = A_i @ (W3top - W3bot) + b3;  Q[j] = A_j @ W3bot
// ---------------------------------------------------------------------------
__global__ void __launch_bounds__(256) node_xform2_kernel(
    const _Float16* __restrict__ B1h,
    const float* __restrict__ W3, const float* __restrict__ b3,
    _Float16* __restrict__ Ph, _Float16* __restrict__ Qh, int nNodes)
{
    const int lane = threadIdx.x & 63;
    const int wave = (blockIdx.x * blockDim.x + threadIdx.x) >> 6;
    const int nw   = (gridDim.x * blockDim.x) >> 6;

    float wd[64], wb[64];
#pragma unroll
    for (int k = 0; k < 64; ++k) {
        wb[k] = W3[(64 + k) * 64 + lane];
        wd[k] = W3[k * 64 + lane] - wb[k];
    }
    const float bb = b3[lane];

    for (int i = wave; i < nNodes; i += nw) {
        const float a = (float)B1h[(size_t)i * 64 + lane];
        float p0 = bb, p1 = 0.f, p2 = 0.f, p3 = 0.f;
        float q0 = 0.f, q1 = 0.f, q2 = 0.f, q3 = 0.f;
#pragma unroll
        for (int k = 0; k < 64; k += 4) {
            float a0 = lane_bcast(a, k);
            float a1 = lane_bcast(a, k + 1);
            float a2 = lane_bcast(a, k + 2);
            float a3 = lane_bcast(a, k + 3);
            p0 = fmaf(a0, wd[k],     p0);  q0 = fmaf(a0, wb[k],     q0);
            p1 = fmaf(a1, wd[k + 1], p1);  q1 = fmaf(a1, wb[k + 1], q1);
            p2 = fmaf(a2, wd[k + 2], p2);  q2 = fmaf(a2, wb[k + 2], q2);
            p3 = fmaf(a3, wd[k + 3], p3);  q3 = fmaf(a3, wb[k + 3], q3);
        }
        Ph[(size_t)i * 64 + lane] = (_Float16)((p0 + p1) + (p2 + p3));
        Qh[(size_t)i * 64 + lane] = (_Float16)((q0 + q1) + (q2 + q3));
    }
}

// ---------------------------------------------------------------------------
// CSR MFMA edge+aggregate (f16), TWO nodes per wave interleaved (measured-best
// config, R13/R15: ~56.5 us/conv, VGPR 60). Pad slots replicate edge deg-1 ->
// unmasked max fold. Output rows stored f16.
// Floor analysis: FETCH ~48 MB = 8 XCDs x 6.4 MB Qh (per-XCD compulsory L2
// misses at L3 latency) -- structural for random f16 gathers.
// C/D layout: row=(lane>>4)*4+reg, col=lane&15 (m89-verified).
// ---------------------------------------------------------------------------
__global__ void __launch_bounds__(256) edge_agg_mfma_kernel(
    const _Float16* __restrict__ Ph, const _Float16* __restrict__ Qh,
    const int2* __restrict__ rowInfo, const int* __restrict__ sortedSrc,
    const float* __restrict__ W, const float* __restrict__ b,
    _Float16* __restrict__ outB, int nNodes)
{
    __shared__ u32x4 wlds[16][64];   // 16 KB: frag f (0-7 wh, 8-15 wl), per lane

    const int tid  = threadIdx.x;
    const int lane = tid & 63;
    const int cn   = lane & 15;   // A: edge slot; B/C: column
    const int q    = lane >> 4;   // quad
    const int wv   = tid >> 6;    // wave in block
    const int wave = (blockIdx.x * 256 + tid) >> 6;
    const int nw   = (gridDim.x * 256) >> 6;

    // cooperative weight-fragment init (frag f: isLo=f>=8, nt=(f&7)>>1, ks=f&1)
#pragma unroll
    for (int i = 0; i < 4; ++i) {
        const int f    = wv + i * 4;
        const int isLo = f >> 3;
        const int g    = f & 7;
        const int nt   = g >> 1;
        const int ks   = g & 1;
        u32x4 d;
#pragma unroll
        for (int p = 0; p < 4; ++p) {
            float w0 = W[(ks * 32 + q * 8 + 2 * p)     * 64 + nt * 16 + cn];
            float w1 = W[(ks * 32 + q * 8 + 2 * p + 1) * 64 + nt * 16 + cn];
            _Float16 h0, l0, h1, l1;
            split_f16(w0, h0, l0);
            split_f16(w1, h1, l1);
            d[p] = isLo ? pack_f16(l0, l1) : pack_f16(h0, h1);
        }
        wlds[f][lane] = d;
    }
    float bc[4];
#pragma unroll
    for (int nt = 0; nt < 4; ++nt) bc[nt] = b[nt * 16 + cn];
    __syncthreads();

    const u32 nClamp = (u32)(nNodes - 1);

    for (int base = wave; base < nNodes; base += 2 * nw) {
        const int n1 = base;
        const int n2 = base + nw;
        const bool has2 = (n2 < nNodes);

        const int2 ri1 = rowInfo[n1];
        const int2 ri2 = has2 ? rowInfo[n2] : make_int2(ri1.x, 0);
        const int rs1  = __builtin_amdgcn_readfirstlane(ri1.x);
        const int deg1 = __builtin_amdgcn_readfirstlane(ri1.y);
        const int rs2  = __builtin_amdgcn_readfirstlane(ri2.x);
        const int deg2 = __builtin_amdgcn_readfirstlane(ri2.y);
        const int d1c = max(deg1, 1) - 1;
        const int d2c = max(deg2, 1) - 1;

        const f16x8* P1 = (const f16x8*)(Ph + (size_t)n1 * 64);
        const f16x8* P2 = (const f16x8*)(Ph + (size_t)(has2 ? n2 : n1) * 64);
        const f16x8 p1A = P1[q], p1B = P1[4 + q];
        const f16x8 p2A = P2[q], p2B = P2[4 + q];

        float m10 = -INFINITY, m11 = -INFINITY, m12 = -INFINITY, m13 = -INFINITY;
        float m20 = -INFINITY, m21 = -INFINITY, m22 = -INFINITY, m23 = -INFINITY;

        const int gmax = max(deg1, deg2);
        for (int g0 = 0; g0 < gmax; g0 += 32) {
            // ---- issue ALL loads (both nodes, both groups) ----
            u32 sA1 = (u32)sortedSrc[rs1 + min(g0 + cn,      d1c)];
            u32 sB1 = (u32)sortedSrc[rs1 + min(g0 + 16 + cn, d1c)];
            u32 sA2 = (u32)sortedSrc[rs2 + min(g0 + cn,      d2c)];
            u32 sB2 = (u32)sortedSrc[rs2 + min(g0 + 16 + cn, d2c)];
            sA1 = min(sA1, nClamp); sB1 = min(sB1, nClamp);   // poison guard
            sA2 = min(sA2, nClamp); sB2 = min(sB2, nClamp);
            const f16x8* QA1 = (const f16x8*)(Qh + (size_t)sA1 * 64);
            const f16x8* QB1 = (const f16x8*)(Qh + (size_t)sB1 * 64);
            const f16x8* QA2 = (const f16x8*)(Qh + (size_t)sA2 * 64);
            const f16x8* QB2 = (const f16x8*)(Qh + (size_t)sB2 * 64);
            const f16x8 qA1a = QA1[q], qA1b = QA1[4 + q];
            const f16x8 qB1a = QB1[q], qB1b = QB1[4 + q];
            const f16x8 qA2a = QA2[q], qA2b = QA2[4 + q];
            const f16x8 qB2a = QB2[q], qB2b = QB2[4 + q];

            // ---- node 1 compute (unmasked fold: pads duplicate edge deg-1) ----
            if (g0 < deg1) {
                const f16x8 A00 = lrelu8(p1A + qA1a);
                const f16x8 A01 = lrelu8(p1B + qA1b);
                const f16x8 A10 = lrelu8(p1A + qB1a);
                const f16x8 A11 = lrelu8(p1B + qB1b);
#pragma unroll
                for (int nt = 0; nt < 4; ++nt) {
                    const f16x8 wh0 = __builtin_bit_cast(f16x8, wlds[nt * 2][lane]);
                    const f16x8 wh1 = __builtin_bit_cast(f16x8, wlds[nt * 2 + 1][lane]);
                    const f16x8 wl0 = __builtin_bit_cast(f16x8, wlds[8 + nt * 2][lane]);
                    const f16x8 wl1 = __builtin_bit_cast(f16x8, wlds[8 + nt * 2 + 1][lane]);
                    f32x4 a; a[0] = a[1] = a[2] = a[3] = bc[nt];
                    a = __builtin_amdgcn_mfma_f32_16x16x32_f16(A00, wl0, a, 0, 0, 0);
                    a = __builtin_amdgcn_mfma_f32_16x16x32_f16(A00, wh0, a, 0, 0, 0);
                    a = __builtin_amdgcn_mfma_f32_16x16x32_f16(A01, wl1, a, 0, 0, 0);
                    a = __builtin_amdgcn_mfma_f32_16x16x32_f16(A01, wh1, a, 0, 0, 0);
                    f32x4 c; c[0] = c[1] = c[2] = c[3] = bc[nt];
                    c = __builtin_amdgcn_mfma_f32_16x16x32_f16(A10, wl0, c, 0, 0, 0);
                    c = __builtin_amdgcn_mfma_f32_16x16x32_f16(A10, wh0, c, 0, 0, 0);
                    c = __builtin_amdgcn_mfma_f32_16x16x32_f16(A11, wl1, c, 0, 0, 0);
                    c = __builtin_amdgcn_mfma_f32_16x16x32_f16(A11, wh1, c, 0, 0, 0);
                    float m = (nt == 0) ? m10 : (nt == 1) ? m11 : (nt == 2) ? m12 : m13;
                    m = fmaxf(m, fmaxf(fmaxf(a[0], a[1]), fmaxf(a[2], a[3])));
                    m = fmaxf(m, fmaxf(fmaxf(c[0], c[1]), fmaxf(c[2], c[3])));
                    if (nt == 0) m10 = m; else if (nt == 1) m11 = m;
                    else if (nt == 2) m12 = m; else m13 = m;
                }
            }
            // ---- node 2 compute ----
            if (g0 < deg2) {
                const f16x8 A00 = lrelu8(p2A + qA2a);
                const f16x8 A01 = lrelu8(p2B + qA2b);
                const f16x8 A10 = lrelu8(p2A + qB2a);
                const f16x8 A11 = lrelu8(p2B + qB2b);
#pragma unroll
                for (int nt = 0; nt < 4; ++nt) {
                    const f16x8 wh0 = __builtin_bit_cast(f16x8, wlds[nt * 2][lane]);
                    const f16x8 wh1 = __builtin_bit_cast(f16x8, wlds[nt * 2 + 1][lane]);
                    const f16x8 wl0 = __builtin_bit_cast(f16x8, wlds[8 + nt * 2][lane]);
                    const f16x8 wl1 = __builtin_bit_cast(f16x8, wlds[8 + nt * 2 + 1][lane]);
                    f32x4 a; a[0] = a[1] = a[2] = a[3] = bc[nt];
                    a = __builtin_amdgcn_mfma_f32_16x16x32_f16(A00, wl0, a, 0, 0, 0);
                    a = __builtin_amdgcn_mfma_f32_16x16x32_f16(A00, wh0, a, 0, 0, 0);
                    a = __builtin_amdgcn_mfma_f32_16x16x32_f16(A01, wl1, a, 0, 0, 0);
                    a = __builtin_amdgcn_mfma_f32_16x16x32_f16(A01, wh1, a, 0, 0, 0);
                    f32x4 c; c[0] = c[1] = c[2] = c[3] = bc[nt];
                    c = __builtin_amdgcn_mfma_f32_16x16x32_f16(A10, wl0, c, 0, 0, 0);
                    c = __builtin_amdgcn_mfma_f32_16x16x32_f16(A10, wh0, c, 0, 0, 0);
                    c = __builtin_amdgcn_mfma_f32_16x16x32_f16(A11, wl1, c, 0, 0, 0);
                    c = __builtin_amdgcn_mfma_f32_16x16x32_f16(A11, wh1, c, 0, 0, 0);
                    float m = (nt == 0) ? m20 : (nt == 1) ? m21 : (nt == 2) ? m22 : m23;
                    m = fmaxf(m, fmaxf(fmaxf(a[0], a[1]), fmaxf(a[2], a[3])));
                    m = fmaxf(m, fmaxf(fmaxf(c[0], c[1]), fmaxf(c[2], c[3])));
                    if (nt == 0) m20 = m; else if (nt == 1) m21 = m;
                    else if (nt == 2) m22 = m; else m23 = m;
                }
            }
        }

        // cross-quad max butterflies + stores (f16)
        m10 = fmaxf(m10, __shfl_xor(m10, 16)); m10 = fmaxf(m10, __shfl_xor(m10, 32));
        m11 = fmaxf(m11, __shfl_xor(m11, 16)); m11 = fmaxf(m11, __shfl_xor(m11, 32));
        m12 = fmaxf(m12, __shfl_xor(m12, 16)); m12 = fmaxf(m12, __shfl_xor(m12, 32));
        m13 = fmaxf(m13, __shfl_xor(m13, 16)); m13 = fmaxf(m13, __shfl_xor(m13, 32));
        float sel1 = (q < 2) ? ((q == 0) ? m10 : m11) : ((q == 2) ? m12 : m13);
        outB[(size_t)n1 * 64 + q * 16 + cn] =
            (_Float16)((deg1 > 0) ? lrelu(sel1) : 0.0f);

        if (has2) {
            m20 = fmaxf(m20, __shfl_xor(m20, 16)); m20 = fmaxf(m20, __shfl_xor(m20, 32));
            m21 = fmaxf(m21, __shfl_xor(m21, 16)); m21 = fmaxf(m21, __shfl_xor(m21, 32));
            m22 = fmaxf(m22, __shfl_xor(m22, 16)); m22 = fmaxf(m22, __shfl_xor(m22, 32));
            m23 = fmaxf(m23, __shfl_xor(m23, 16)); m23 = fmaxf(m23, __shfl_xor(m23, 32));
            float sel2 = (q < 2) ? ((q == 0) ? m20 : m21) : ((q == 2) ? m22 : m23);
            outB[(size_t)n2 * 64 + q * 16 + cn] =
                (_Float16)((deg2 > 0) ? lrelu(sel2) : 0.0f);
        }
    }
}

__device__ __forceinline__ int lower_bound_i(const int* __restrict__ a, int n, int key)
{
    int lo = 0, hi = n;
    while (lo < hi) {
        int mid = (lo + hi) >> 1;
        if (a[mid] < key) lo = mid + 1; else hi = mid;
    }
    return lo;
}

// PPARTS blocks per graph (1024 blocks, streaming-BW bound), f16 input.
__global__ void __launch_bounds__(256) pool_kernel(
    const _Float16* __restrict__ Bh, const int* __restrict__ batch,
    float* __restrict__ gpart, int nNodes)
{
    const int gid  = blockIdx.x / PPARTS;
    const int part = blockIdx.x % PPARTS;
    const int c    = threadIdx.x & 63;
    const int wid  = threadIdx.x >> 6;

    const int s = lower_bound_i(batch, nNodes, gid);
    const int e = lower_bound_i(batch, nNodes, gid + 1);
    const int len = e - s;
    const int ps = s + (len * part) / PPARTS;
    const int pe = s + (len * (part + 1)) / PPARTS;

    float sum = 0.f, mx = -INFINITY;
    for (int n = ps + wid; n < pe; n += 4) {
        float v = (float)Bh[(size_t)n * 64 + c];
        sum += v;
        mx = fmaxf(mx, v);
    }
    __shared__ float ssum[4][64];
    __shared__ float smax[4][64];
    ssum[wid][c] = sum;
    smax[wid][c] = mx;
    __syncthreads();
    if (wid == 0) {
        sum = (ssum[0][c] + ssum[1][c]) + (ssum[2][c] + ssum[3][c]);
        mx  = fmaxf(fmaxf(smax[0][c], smax[1][c]), fmaxf(smax[2][c], smax[3][c]));
        float* row = gpart + (size_t)blockIdx.x * 132;
        row[c]      = sum;
        row[64 + c] = mx;
        if (c == 0) row[128] = (float)(pe - ps);
    }
}

// One wave per graph: combine PPARTS pool partials, then classifier head.
__global__ void __launch_bounds__(64) cls_kernel(
    const float* __restrict__ gpart,
    const float* __restrict__ Wc1, const float* __restrict__ bc1,
    const float* __restrict__ Wc2, const float* __restrict__ bc2,
    float* __restrict__ out)
{
    __shared__ float g[128];
    const int gid = blockIdx.x;
    const int c   = threadIdx.x;

    float s = 0.f, m = -INFINITY, cnt = 0.f;
#pragma unroll
    for (int p = 0; p < PPARTS; ++p) {
        const float* row = gpart + (size_t)(gid * PPARTS + p) * 132;
        s += row[c];
        m = fmaxf(m, row[64 + c]);
        cnt += row[128];
    }
    g[c]      = s / fmaxf(cnt, 1.0f);
    g[64 + c] = (cnt > 0.f) ? m : 0.0f;
    __syncthreads();

    float t = bc1[c];
#pragma unroll 8
    for (int k = 0; k < 128; ++k) t = fmaf(g[k], Wc1[k * 64 + c], t);
    t = lrelu(t);
    float p = t * Wc2[c];
#pragma unroll
    for (int off = 32; off > 0; off >>= 1) p += __shfl_down(p, off);
    if (c == 0) out[gid] = p + bc2[0];
}

static inline size_t align_up(size_t v, size_t a) { return (v + a - 1) & ~(a - 1); }

extern "C" void kernel_launch(void* const* d_in, const int* in_sizes, int n_in,
                              void* d_out, int out_size, void* d_ws, size_t ws_size,
                              hipStream_t stream)
{
    const float* x     = (const float*)d_in[0];
    const int*   ei    = (const int*)d_in[1];
    const int*   batch = (const int*)d_in[2];
    const float* W1  = (const float*)d_in[3];
    const float* b1  = (const float*)d_in[4];
    const float* W2  = (const float*)d_in[5];
    const float* b2  = (const float*)d_in[6];
    const float* W3  = (const float*)d_in[7];
    const float* b3  = (const float*)d_in[8];
    const float* W4  = (const float*)d_in[9];
    const float* b4  = (const float*)d_in[10];
    const float* Wc1 = (const float*)d_in[11];
    const float* bc1 = (const float*)d_in[12];
    const float* Wc2 = (const float*)d_in[13];
    const float* bc2 = (const float*)d_in[14];
    float* out = (float*)d_out;

    const int nNodes  = in_sizes[0] / 6;
    const int E       = in_sizes[1] / 2;
    const int nGraphs = out_size;
    const int* srcI = ei;
    const int* dstI = ei + E;
    const int nBuck = (nNodes + NPB - 1) / NPB;
    const int nCntB = (E + EPB - 1) / EPB;

    // workspace carve-up (256B-aligned)
    char* wsp = (char*)d_ws;
    size_t off = 0;
    int*  cursor    = (int*)(wsp + off);   off = align_up(off + (size_t)MAXBUCK * 8 * 4, 256);
    int2* rowInfo   = (int2*)(wsp + off);  off = align_up(off + (size_t)nNodes * 8, 256);
    int*  sortedSrc = (int*)(wsp + off);   off = align_up(off + (size_t)nBuck * CAP * 4, 256);
    u32*  pairW     = (u32*)(wsp + off);   off = align_up(off + (size_t)nBuck * 8 * SUBCAP * 4, 256);
    const size_t nFeat = (size_t)nNodes * 64;
    _Float16* Ph   = (_Float16*)(wsp + off);  off = align_up(off + nFeat * 2, 256);
    _Float16* Qh   = (_Float16*)(wsp + off);  off = align_up(off + nFeat * 2, 256);
    _Float16* B1h  = (_Float16*)(wsp + off);  off = align_up(off + nFeat * 2, 256);
    _Float16* B2h  = (_Float16*)(wsp + off);  off = align_up(off + nFeat * 2, 256);
    float*    gpart= (float*)(wsp + off);     off = align_up(off + (size_t)nGraphs * PPARTS * 132 * 4, 256);
    (void)ws_size;

    // ---- CSR build (full-line scatter runs) + conv1 transform ----
    (void)hipMemsetAsync(cursor, 0, (size_t)nBuck * 8 * 4, stream);
    scatter_xform1_kernel<<<nCntB + XF1B, 256, 0, stream>>>(
        srcI, dstI, cursor, pairW, E, nNodes, nBuck, nCntB, x, W1, b1, Ph, Qh);
    bucket_sort_kernel<<<nBuck, 256, 0, stream>>>(pairW, cursor, rowInfo,
                                                  sortedSrc, nNodes);

    // ---- conv1 edge+agg ----
    edge_agg_mfma_kernel<<<2048, 256, 0, stream>>>(Ph, Qh, rowInfo, sortedSrc,
                                                   W2, b2, B1h, nNodes);
    // ---- conv2 ----
    node_xform2_kernel<<<2048, 256, 0, stream>>>(B1h, W3, b3, Ph, Qh, nNodes);
    edge_agg_mfma_kernel<<<2048, 256, 0, stream>>>(Ph, Qh, rowInfo, sortedSrc,
                                                   W4, b4, B2h, nNodes);

    // ---- pooling + classifier head ----
    pool_kernel<<<nGraphs * PPARTS, 256, 0, stream>>>(B2h, batch, gpart, nNodes);
    cls_kernel<<<nGraphs, 64, 0, stream>>>(gpart, Wc1, bc1, Wc2, bc2, out);
}

// Round 17
// 268.543 us; speedup vs baseline: 1.1198x; 1.1198x over previous
//
#include <hip/hip_runtime.h>
#include <hip/hip_bf16.h>

#define SLOPE 0.2f
#define NPB 64            // nodes per sort bucket
#define CAP 2048          // sortedSrc slots per bucket (mean 1638, 10 sigma)
#define SUBCAP 384        // pairW slots per (bucket, blockgroup) window
#define MAXBUCK 1024
#define EPB 4096          // edges per scatter chunk (R15-proven parallelism)
#define XF1B 512          // xform1 blocks (merged launch)
#define PPARTS 16         // pool partials per graph

typedef _Float16 f16x8  __attribute__((ext_vector_type(8)));
typedef float    f32x4  __attribute__((ext_vector_type(4)));
typedef unsigned u32;
typedef unsigned u32x4  __attribute__((ext_vector_type(4)));

__device__ __forceinline__ float lrelu(float v) { return fmaxf(v, SLOPE * v); }

__device__ __forceinline__ float lane_bcast(float v, int k) {
    return __int_as_float(__builtin_amdgcn_readlane(__float_as_int(v), k));
}

// packed f16 leaky-relu: max(v, 0.2*v) elementwise
__device__ __forceinline__ f16x8 lrelu8(f16x8 v) {
    f16x8 s = v * (_Float16)SLOPE;
#if __has_builtin(__builtin_elementwise_max)
    return __builtin_elementwise_max(v, s);
#else
    f16x8 r;
#pragma unroll
    for (int i = 0; i < 8; ++i) r[i] = v[i] > s[i] ? v[i] : s[i];
    return r;
#endif
}

// f32 -> (hi, lo) f16 split; hi+lo reproduces v to ~2^-22.
__device__ __forceinline__ void split_f16(float v, _Float16& h, _Float16& l) {
    h = (_Float16)v;
    l = (_Float16)(v - (float)h);
}
__device__ __forceinline__ u32 pack_f16(_Float16 a, _Float16 b) {
    return (u32)__builtin_bit_cast(unsigned short, a) |
           ((u32)__builtin_bit_cast(unsigned short, b) << 16);
}

// ---------------------------------------------------------------------------
// Merged launch: blocks [0,nCntB) counting-sort a 4096-edge chunk into 8-way
// sub-cursor bucket windows of pairW. Phases vectorized: int4 edge loads ->
// 4 independent LDS-atomic chains per thread (R16 showed VALUBusy 3%: the
// old scalar loop had ONE dependent chain in flight).
// Blocks [nCntB,..): conv1 node transform (f16 out).
// ---------------------------------------------------------------------------
__global__ void __launch_bounds__(256) scatter_xform1_kernel(
    const int* __restrict__ srcI, const int* __restrict__ dstI,
    int* __restrict__ cursor, u32* __restrict__ pairW,
    int E, int nNodes, int nBuck, int nCntB,
    const float* __restrict__ x,
    const float* __restrict__ W1, const float* __restrict__ b1,
    _Float16* __restrict__ Ph, _Float16* __restrict__ Qh)
{
    if (blockIdx.x < nCntB) {
        __shared__ int cnt[MAXBUCK];
        __shared__ int base[MAXBUCK];
        const int tid = threadIdx.x;
        const int j   = blockIdx.x & 7;          // sub-cursor group (~XCD)
        const int e0 = blockIdx.x * EPB;
        const int e1 = min(e0 + EPB, E);
        const int n4 = (e1 - e0) >> 2;           // vectorizable quads
        const int4* d4 = (const int4*)(dstI + e0);
        const int4* s4 = (const int4*)(srcI + e0);

        for (int b = tid; b < nBuck; b += 256) cnt[b] = 0;
        __syncthreads();
        for (int i = tid; i < n4; i += 256) {
            const int4 d = d4[i];
            atomicAdd(&cnt[d.x >> 6], 1);
            atomicAdd(&cnt[d.y >> 6], 1);
            atomicAdd(&cnt[d.z >> 6], 1);
            atomicAdd(&cnt[d.w >> 6], 1);
        }
        for (int e = e0 + (n4 << 2) + tid; e < e1; e += 256)   // tail
            atomicAdd(&cnt[dstI[e] >> 6], 1);
        __syncthreads();
        for (int b = tid; b < nBuck; b += 256) {
            int c = cnt[b];
            base[b] = (c > 0)
                ? ((b * 8 + j) * SUBCAP + min(atomicAdd(&cursor[b * 8 + j], c), SUBCAP))
                : 0;
            cnt[b] = 0;
        }
        __syncthreads();
        for (int i = tid; i < n4; i += 256) {
            const int4 d = d4[i];
            const int4 s = s4[i];
            {
                const int b = d.x >> 6;
                const int loc = atomicAdd(&cnt[b], 1);
                pairW[min(base[b] + loc, (b * 8 + j + 1) * SUBCAP - 1)] =
                    ((u32)s.x << 6) | (u32)(d.x & (NPB - 1));
            }
            {
                const int b = d.y >> 6;
                const int loc = atomicAdd(&cnt[b], 1);
                pairW[min(base[b] + loc, (b * 8 + j + 1) * SUBCAP - 1)] =
                    ((u32)s.y << 6) | (u32)(d.y & (NPB - 1));
            }
            {
                const int b = d.z >> 6;
                const int loc = atomicAdd(&cnt[b], 1);
                pairW[min(base[b] + loc, (b * 8 + j + 1) * SUBCAP - 1)] =
                    ((u32)s.z << 6) | (u32)(d.z & (NPB - 1));
            }
            {
                const int b = d.w >> 6;
                const int loc = atomicAdd(&cnt[b], 1);
                pairW[min(base[b] + loc, (b * 8 + j + 1) * SUBCAP - 1)] =
                    ((u32)s.w << 6) | (u32)(d.w & (NPB - 1));
            }
        }
        for (int e = e0 + (n4 << 2) + tid; e < e1; e += 256) { // tail
            const int d = dstI[e];
            const int b = d >> 6;
            const int loc = atomicAdd(&cnt[b], 1);
            pairW[min(base[b] + loc, (b * 8 + j + 1) * SUBCAP - 1)] =
                ((u32)srcI[e] << 6) | (u32)(d & (NPB - 1));
        }
        return;
    }
    const int lane = threadIdx.x & 63;
    const int wave = ((blockIdx.x - nCntB) * 256 + threadIdx.x) >> 6;
    const int nw   = (XF1B * 256) >> 6;

    float wd[6], wb[6];
#pragma unroll
    for (int r = 0; r < 6; ++r) {
        wb[r] = W1[(6 + r) * 64 + lane];
        wd[r] = W1[r * 64 + lane] - wb[r];
    }
    const float bb = b1[lane];
    for (int i = wave; i < nNodes; i += nw) {
        const float* xr = x + (size_t)i * 6;
        float p = bb, q = 0.f;
#pragma unroll
        for (int r = 0; r < 6; ++r) {
            float xv = xr[r];
            p = fmaf(xv, wd[r], p);
            q = fmaf(xv, wb[r], q);
        }
        Ph[(size_t)i * 64 + lane] = (_Float16)p;
        Qh[(size_t)i * 64 + lane] = (_Float16)q;
    }
}

// One block per bucket: compact the 8 sub-windows into LDS once (u32x4
// global loads), then count + scatter passes run entirely LDS->LDS (no
// second 5 MB global read, no global latency per pair).
__global__ void __launch_bounds__(256) bucket_sort_kernel(
    const u32* __restrict__ pairW, const int* __restrict__ cursor,
    int2* __restrict__ rowInfo, int* __restrict__ sortedSrc, int nNodes)
{
    __shared__ u32 pairLds[CAP];
    __shared__ int nodeCnt[NPB];
    __shared__ int nodeCur[NPB];
    __shared__ int wcS[8];
    __shared__ int wBase[9];
    const int b   = blockIdx.x;
    const int n0  = b * NPB;
    const int n1  = min(n0 + NPB, nNodes);
    const int tid = threadIdx.x;

    if (tid < NPB) nodeCnt[tid] = 0;
    if (tid < 8) wcS[tid] = min(cursor[b * 8 + tid], SUBCAP);
    __syncthreads();
    if (tid == 0) {
        int acc = 0;
#pragma unroll
        for (int jj = 0; jj < 8; ++jj) { wBase[jj] = acc; acc += wcS[jj]; }
        wBase[8] = acc;
    }
    __syncthreads();

    // compact sub-windows into pairLds (vector global loads, LDS stores)
#pragma unroll
    for (int jj = 0; jj < 8; ++jj) {
        const int w0 = (b * 8 + jj) * SUBCAP;
        const int wc = wcS[jj];
        const int d0 = wBase[jj];
        const int nv = wc >> 2;
        const u32x4* p4 = (const u32x4*)(pairW + w0);
        for (int i = tid; i < nv; i += 256) {
            const u32x4 v = p4[i];
            pairLds[d0 + i * 4 + 0] = v[0];
            pairLds[d0 + i * 4 + 1] = v[1];
            pairLds[d0 + i * 4 + 2] = v[2];
            pairLds[d0 + i * 4 + 3] = v[3];
        }
        for (int i = (nv << 2) + tid; i < wc; i += 256)
            pairLds[d0 + i] = pairW[w0 + i];
    }
    __syncthreads();

    const int total = wBase[8];
    for (int i = tid; i < total; i += 256)           // LDS->LDS count
        atomicAdd(&nodeCnt[pairLds[i] & (NPB - 1)], 1);
    __syncthreads();
    if (tid < 64) {                       // wave 0: prefix scan of 64 counts
        const int c = nodeCnt[tid];
        int inc = c;
#pragma unroll
        for (int off = 1; off < 64; off <<= 1) {
            int t = __shfl_up(inc, off);
            if (tid >= off) inc += t;
        }
        const int st = b * CAP + inc - c; // exclusive, bucket-window-local
        nodeCur[tid] = st;
        if (tid < n1 - n0) rowInfo[n0 + tid] = make_int2(st, c);
    }
    __syncthreads();
    for (int i = tid; i < total; i += 256) {         // LDS read, global write
        const u32 w = pairLds[i];
        const int pos = atomicAdd(&nodeCur[w & (NPB - 1)], 1);
        sortedSrc[pos] = (int)(w >> 6);
    }
}

// ---------------------------------------------------------------------------
// Node transform for conv2 (f16 in/out, VALU readlane -- R13-proven):
//   P[i] = A_i @ (W3top - W3bot) + b3;  Q[j] = A_j @ W3bot
// ---------------------------------------------------------------------------
__global__ void __launch_bounds__(256) node_xform2_kernel(
    const _Float16* __restrict__ B1h,
    const float* __restrict__ W3, const float* __restrict__ b3,
    _Float16* __restrict__ Ph, _Float16* __restrict__ Qh, int nNodes)
{
    const int lane = threadIdx.x & 63;
    const int wave = (blockIdx.x * blockDim.x + threadIdx.x) >> 6;
    const int nw   = (gridDim.x * blockDim.x) >> 6;

    float wd[64], wb[64];
#pragma unroll
    for (int k = 0; k < 64; ++k) {
        wb[k] = W3[(64 + k) * 64 + lane];
        wd[k] = W3[k * 64 + lane] - wb[k];
    }
    const float bb = b3[lane];

    for (int i = wave; i < nNodes; i += nw) {
        const float a = (float)B1h[(size_t)i * 64 + lane];
        float p0 = bb, p1 = 0.f, p2 = 0.f, p3 = 0.f;
        float q0 = 0.f, q1 = 0.f, q2 = 0.f, q3 = 0.f;
#pragma unroll
        for (int k = 0; k < 64; k += 4) {
            float a0 = lane_bcast(a, k);
            float a1 = lane_bcast(a, k + 1);
            float a2 = lane_bcast(a, k + 2);
            float a3 = lane_bcast(a, k + 3);
            p0 = fmaf(a0, wd[k],     p0);  q0 = fmaf(a0, wb[k],     q0);
            p1 = fmaf(a1, wd[k + 1], p1);  q1 = fmaf(a1, wb[k + 1], q1);
            p2 = fmaf(a2, wd[k + 2], p2);  q2 = fmaf(a2, wb[k + 2], q2);
            p3 = fmaf(a3, wd[k + 3], p3);  q3 = fmaf(a3, wb[k + 3], q3);
        }
        Ph[(size_t)i * 64 + lane] = (_Float16)((p0 + p1) + (p2 + p3));
        Qh[(size_t)i * 64 + lane] = (_Float16)((q0 + q1) + (q2 + q3));
    }
}

// ---------------------------------------------------------------------------
// CSR MFMA edge+aggregate (f16), TWO nodes per wave interleaved (measured-best
// config, R13/R15: ~56.5 us/conv, VGPR 60). Pad slots replicate edge deg-1 ->
// unmasked max fold. Output rows stored f16.
// Floor analysis: FETCH ~48 MB = 8 XCDs x 6.4 MB Qh (per-XCD compulsory L2
// misses at L3 latency) -- structural for random f16 gathers.
// C/D layout: row=(lane>>4)*4+reg, col=lane&15 (m89-verified).
// ---------------------------------------------------------------------------
__global__ void __launch_bounds__(256) edge_agg_mfma_kernel(
    const _Float16* __restrict__ Ph, const _Float16* __restrict__ Qh,
    const int2* __restrict__ rowInfo, const int* __restrict__ sortedSrc,
    const float* __restrict__ W, const float* __restrict__ b,
    _Float16* __restrict__ outB, int nNodes)
{
    __shared__ u32x4 wlds[16][64];   // 16 KB: frag f (0-7 wh, 8-15 wl), per lane

    const int tid  = threadIdx.x;
    const int lane = tid & 63;
    const int cn   = lane & 15;   // A: edge slot; B/C: column
    const int q    = lane >> 4;   // quad
    const int wv   = tid >> 6;    // wave in block
    const int wave = (blockIdx.x * 256 + tid) >> 6;
    const int nw   = (gridDim.x * 256) >> 6;

    // cooperative weight-fragment init (frag f: isLo=f>=8, nt=(f&7)>>1, ks=f&1)
#pragma unroll
    for (int i = 0; i < 4; ++i) {
        const int f    = wv + i * 4;
        const int isLo = f >> 3;
        const int g    = f & 7;
        const int nt   = g >> 1;
        const int ks   = g & 1;
        u32x4 d;
#pragma unroll
        for (int p = 0; p < 4; ++p) {
            float w0 = W[(ks * 32 + q * 8 + 2 * p)     * 64 + nt * 16 + cn];
            float w1 = W[(ks * 32 + q * 8 + 2 * p + 1) * 64 + nt * 16 + cn];
            _Float16 h0, l0, h1, l1;
            split_f16(w0, h0, l0);
            split_f16(w1, h1, l1);
            d[p] = isLo ? pack_f16(l0, l1) : pack_f16(h0, h1);
        }
        wlds[f][lane] = d;
    }
    float bc[4];
#pragma unroll
    for (int nt = 0; nt < 4; ++nt) bc[nt] = b[nt * 16 + cn];
    __syncthreads();

    const u32 nClamp = (u32)(nNodes - 1);

    for (int base = wave; base < nNodes; base += 2 * nw) {
        const int n1 = base;
        const int n2 = base + nw;
        const bool has2 = (n2 < nNodes);

        const int2 ri1 = rowInfo[n1];
        const int2 ri2 = has2 ? rowInfo[n2] : make_int2(ri1.x, 0);
        const int rs1  = __builtin_amdgcn_readfirstlane(ri1.x);
        const int deg1 = __builtin_amdgcn_readfirstlane(ri1.y);
        const int rs2  = __builtin_amdgcn_readfirstlane(ri2.x);
        const int deg2 = __builtin_amdgcn_readfirstlane(ri2.y);
        const int d1c = max(deg1, 1) - 1;
        const int d2c = max(deg2, 1) - 1;

        const f16x8* P1 = (const f16x8*)(Ph + (size_t)n1 * 64);
        const f16x8* P2 = (const f16x8*)(Ph + (size_t)(has2 ? n2 : n1) * 64);
        const f16x8 p1A = P1[q], p1B = P1[4 + q];
        const f16x8 p2A = P2[q], p2B = P2[4 + q];

        float m10 = -INFINITY, m11 = -INFINITY, m12 = -INFINITY, m13 = -INFINITY;
        float m20 = -INFINITY, m21 = -INFINITY, m22 = -INFINITY, m23 = -INFINITY;

        const int gmax = max(deg1, deg2);
        for (int g0 = 0; g0 < gmax; g0 += 32) {
            // ---- issue ALL loads (both nodes, both groups) ----
            u32 sA1 = (u32)sortedSrc[rs1 + min(g0 + cn,      d1c)];
            u32 sB1 = (u32)sortedSrc[rs1 + min(g0 + 16 + cn, d1c)];
            u32 sA2 = (u32)sortedSrc[rs2 + min(g0 + cn,      d2c)];
            u32 sB2 = (u32)sortedSrc[rs2 + min(g0 + 16 + cn, d2c)];
            sA1 = min(sA1, nClamp); sB1 = min(sB1, nClamp);   // poison guard
            sA2 = min(sA2, nClamp); sB2 = min(sB2, nClamp);
            const f16x8* QA1 = (const f16x8*)(Qh + (size_t)sA1 * 64);
            const f16x8* QB1 = (const f16x8*)(Qh + (size_t)sB1 * 64);
            const f16x8* QA2 = (const f16x8*)(Qh + (size_t)sA2 * 64);
            const f16x8* QB2 = (const f16x8*)(Qh + (size_t)sB2 * 64);
            const f16x8 qA1a = QA1[q], qA1b = QA1[4 + q];
            const f16x8 qB1a = QB1[q], qB1b = QB1[4 + q];
            const f16x8 qA2a = QA2[q], qA2b = QA2[4 + q];
            const f16x8 qB2a = QB2[q], qB2b = QB2[4 + q];

            // ---- node 1 compute (unmasked fold: pads duplicate edge deg-1) ----
            if (g0 < deg1) {
                const f16x8 A00 = lrelu8(p1A + qA1a);
                const f16x8 A01 = lrelu8(p1B + qA1b);
                const f16x8 A10 = lrelu8(p1A + qB1a);
                const f16x8 A11 = lrelu8(p1B + qB1b);
#pragma unroll
                for (int nt = 0; nt < 4; ++nt) {
                    const f16x8 wh0 = __builtin_bit_cast(f16x8, wlds[nt * 2][lane]);
                    const f16x8 wh1 = __builtin_bit_cast(f16x8, wlds[nt * 2 + 1][lane]);
                    const f16x8 wl0 = __builtin_bit_cast(f16x8, wlds[8 + nt * 2][lane]);
                    const f16x8 wl1 = __builtin_bit_cast(f16x8, wlds[8 + nt * 2 + 1][lane]);
                    f32x4 a; a[0] = a[1] = a[2] = a[3] = bc[nt];
                    a = __builtin_amdgcn_mfma_f32_16x16x32_f16(A00, wl0, a, 0, 0, 0);
                    a = __builtin_amdgcn_mfma_f32_16x16x32_f16(A00, wh0, a, 0, 0, 0);
                    a = __builtin_amdgcn_mfma_f32_16x16x32_f16(A01, wl1, a, 0, 0, 0);
                    a = __builtin_amdgcn_mfma_f32_16x16x32_f16(A01, wh1, a, 0, 0, 0);
                    f32x4 c; c[0] = c[1] = c[2] = c[3] = bc[nt];
                    c = __builtin_amdgcn_mfma_f32_16x16x32_f16(A10, wl0, c, 0, 0, 0);
                    c = __builtin_amdgcn_mfma_f32_16x16x32_f16(A10, wh0, c, 0, 0, 0);
                    c = __builtin_amdgcn_mfma_f32_16x16x32_f16(A11, wl1, c, 0, 0, 0);
                    c = __builtin_amdgcn_mfma_f32_16x16x32_f16(A11, wh1, c, 0, 0, 0);
                    float m = (nt == 0) ? m10 : (nt == 1) ? m11 : (nt == 2) ? m12 : m13;
                    m = fmaxf(m, fmaxf(fmaxf(a[0], a[1]), fmaxf(a[2], a[3])));
                    m = fmaxf(m, fmaxf(fmaxf(c[0], c[1]), fmaxf(c[2], c[3])));
                    if (nt == 0) m10 = m; else if (nt == 1) m11 = m;
                    else if (nt == 2) m12 = m; else m13 = m;
                }
            }
            // ---- node 2 compute ----
            if (g0 < deg2) {
                const f16x8 A00 = lrelu8(p2A + qA2a);
                const f16x8 A01 = lrelu8(p2B + qA2b);
                const f16x8 A10 = lrelu8(p2A + qB2a);
                const f16x8 A11 = lrelu8(p2B + qB2b);
#pragma unroll
                for (int nt = 0; nt < 4; ++nt) {
                    const f16x8 wh0 = __builtin_bit_cast(f16x8, wlds[nt * 2][lane]);
                    const f16x8 wh1 = __builtin_bit_cast(f16x8, wlds[nt * 2 + 1][lane]);
                    const f16x8 wl0 = __builtin_bit_cast(f16x8, wlds[8 + nt * 2][lane]);
                    const f16x8 wl1 = __builtin_bit_cast(f16x8, wlds[8 + nt * 2 + 1][lane]);
                    f32x4 a; a[0] = a[1] = a[2] = a[3] = bc[nt];
                    a = __builtin_amdgcn_mfma_f32_16x16x32_f16(A00, wl0, a, 0, 0, 0);
                    a = __builtin_amdgcn_mfma_f32_16x16x32_f16(A00, wh0, a, 0, 0, 0);
                    a = __builtin_amdgcn_mfma_f32_16x16x32_f16(A01, wl1, a, 0, 0, 0);
                    a = __builtin_amdgcn_mfma_f32_16x16x32_f16(A01, wh1, a, 0, 0, 0);
                    f32x4 c; c[0] = c[1] = c[2] = c[3] = bc[nt];
                    c = __builtin_amdgcn_mfma_f32_16x16x32_f16(A10, wl0, c, 0, 0, 0);
                    c = __builtin_amdgcn_mfma_f32_16x16x32_f16(A10, wh0, c, 0, 0, 0);
                    c = __builtin_amdgcn_mfma_f32_16x16x32_f16(A11, wl1, c, 0, 0, 0);
                    c = __builtin_amdgcn_mfma_f32_16x16x32_f16(A11, wh1, c, 0, 0, 0);
                    float m = (nt == 0) ? m20 : (nt == 1) ? m21 : (nt == 2) ? m22 : m23;
                    m = fmaxf(m, fmaxf(fmaxf(a[0], a[1]), fmaxf(a[2], a[3])));
                    m = fmaxf(m, fmaxf(fmaxf(c[0], c[1]), fmaxf(c[2], c[3])));
                    if (nt == 0) m20 = m; else if (nt == 1) m21 = m;
                    else if (nt == 2) m22 = m; else m23 = m;
                }
            }
        }

        // cross-quad max butterflies + stores (f16)
        m10 = fmaxf(m10, __shfl_xor(m10, 16)); m10 = fmaxf(m10, __shfl_xor(m10, 32));
        m11 = fmaxf(m11, __shfl_xor(m11, 16)); m11 = fmaxf(m11, __shfl_xor(m11, 32));
        m12 = fmaxf(m12, __shfl_xor(m12, 16)); m12 = fmaxf(m12, __shfl_xor(m12, 32));
        m13 = fmaxf(m13, __shfl_xor(m13, 16)); m13 = fmaxf(m13, __shfl_xor(m13, 32));
        float sel1 = (q < 2) ? ((q == 0) ? m10 : m11) : ((q == 2) ? m12 : m13);
        outB[(size_t)n1 * 64 + q * 16 + cn] =
            (_Float16)((deg1 > 0) ? lrelu(sel1) : 0.0f);

        if (has2) {
            m20 = fmaxf(m20, __shfl_xor(m20, 16)); m20 = fmaxf(m20, __shfl_xor(m20, 32));
            m21 = fmaxf(m21, __shfl_xor(m21, 16)); m21 = fmaxf(m21, __shfl_xor(m21, 32));
            m22 = fmaxf(m22, __shfl_xor(m22, 16)); m22 = fmaxf(m22, __shfl_xor(m22, 32));
            m23 = fmaxf(m23, __shfl_xor(m23, 16)); m23 = fmaxf(m23, __shfl_xor(m23, 32));
            float sel2 = (q < 2) ? ((q == 0) ? m20 : m21) : ((q == 2) ? m22 : m23);
            outB[(size_t)n2 * 64 + q * 16 + cn] =
                (_Float16)((deg2 > 0) ? lrelu(sel2) : 0.0f);
        }
    }
}

__device__ __forceinline__ int lower_bound_i(const int* __restrict__ a, int n, int key)
{
    int lo = 0, hi = n;
    while (lo < hi) {
        int mid = (lo + hi) >> 1;
        if (a[mid] < key) lo = mid + 1; else hi = mid;
    }
    return lo;
}

// PPARTS blocks per graph (1024 blocks, streaming-BW bound), f16 input.
__global__ void __launch_bounds__(256) pool_kernel(
    const _Float16* __restrict__ Bh, const int* __restrict__ batch,
    float* __restrict__ gpart, int nNodes)
{
    const int gid  = blockIdx.x / PPARTS;
    const int part = blockIdx.x % PPARTS;
    const int c    = threadIdx.x & 63;
    const int wid  = threadIdx.x >> 6;

    const int s = lower_bound_i(batch, nNodes, gid);
    const int e = lower_bound_i(batch, nNodes, gid + 1);
    const int len = e - s;
    const int ps = s + (len * part) / PPARTS;
    const int pe = s + (len * (part + 1)) / PPARTS;

    float sum = 0.f, mx = -INFINITY;
    for (int n = ps + wid; n < pe; n += 4) {
        float v = (float)Bh[(size_t)n * 64 + c];
        sum += v;
        mx = fmaxf(mx, v);
    }
    __shared__ float ssum[4][64];
    __shared__ float smax[4][64];
    ssum[wid][c] = sum;
    smax[wid][c] = mx;
    __syncthreads();
    if (wid == 0) {
        sum = (ssum[0][c] + ssum[1][c]) + (ssum[2][c] + ssum[3][c]);
        mx  = fmaxf(fmaxf(smax[0][c], smax[1][c]), fmaxf(smax[2][c], smax[3][c]));
        float* row = gpart + (size_t)blockIdx.x * 132;
        row[c]      = sum;
        row[64 + c] = mx;
        if (c == 0) row[128] = (float)(pe - ps);
    }
}

// One wave per graph: combine PPARTS pool partials, then classifier head.
__global__ void __launch_bounds__(64) cls_kernel(
    const float* __restrict__ gpart,
    const float* __restrict__ Wc1, const float* __restrict__ bc1,
    const float* __restrict__ Wc2, const float* __restrict__ bc2,
    float* __restrict__ out)
{
    __shared__ float g[128];
    const int gid = blockIdx.x;
    const int c   = threadIdx.x;

    float s = 0.f, m = -INFINITY, cnt = 0.f;
#pragma unroll
    for (int p = 0; p < PPARTS; ++p) {
        const float* row = gpart + (size_t)(gid * PPARTS + p) * 132;
        s += row[c];
        m = fmaxf(m, row[64 + c]);
        cnt += row[128];
    }
    g[c]      = s / fmaxf(cnt, 1.0f);
    g[64 + c] = (cnt > 0.f) ? m : 0.0f;
    __syncthreads();

    float t = bc1[c];
#pragma unroll 8
    for (int k = 0; k < 128; ++k) t = fmaf(g[k], Wc1[k * 64 + c], t);
    t = lrelu(t);
    float p = t * Wc2[c];
#pragma unroll
    for (int off = 32; off > 0; off >>= 1) p += __shfl_down(p, off);
    if (c == 0) out[gid] = p + bc2[0];
}

static inline size_t align_up(size_t v, size_t a) { return (v + a - 1) & ~(a - 1); }

extern "C" void kernel_launch(void* const* d_in, const int* in_sizes, int n_in,
                              void* d_out, int out_size, void* d_ws, size_t ws_size,
                              hipStream_t stream)
{
    const float* x     = (const float*)d_in[0];
    const int*   ei    = (const int*)d_in[1];
    const int*   batch = (const int*)d_in[2];
    const float* W1  = (const float*)d_in[3];
    const float* b1  = (const float*)d_in[4];
    const float* W2  = (const float*)d_in[5];
    const float* b2  = (const float*)d_in[6];
    const float* W3  = (const float*)d_in[7];
    const float* b3  = (const float*)d_in[8];
    const float* W4  = (const float*)d_in[9];
    const float* b4  = (const float*)d_in[10];
    const float* Wc1 = (const float*)d_in[11];
    const float* bc1 = (const float*)d_in[12];
    const float* Wc2 = (const float*)d_in[13];
    const float* bc2 = (const float*)d_in[14];
    float* out = (float*)d_out;

    const int nNodes  = in_sizes[0] / 6;
    const int E       = in_sizes[1] / 2;
    const int nGraphs = out_size;
    const int* srcI = ei;
    const int* dstI = ei + E;
    const int nBuck = (nNodes + NPB - 1) / NPB;
    const int nCntB = (E + EPB - 1) / EPB;

    // workspace carve-up (256B-aligned)
    char* wsp = (char*)d_ws;
    size_t off = 0;
    int*  cursor    = (int*)(wsp + off);   off = align_up(off + (size_t)MAXBUCK * 8 * 4, 256);
    int2* rowInfo   = (int2*)(wsp + off);  off = align_up(off + (size_t)nNodes * 8, 256);
    int*  sortedSrc = (int*)(wsp + off);   off = align_up(off + (size_t)nBuck * CAP * 4, 256);
    u32*  pairW     = (u32*)(wsp + off);   off = align_up(off + (size_t)nBuck * 8 * SUBCAP * 4, 256);
    const size_t nFeat = (size_t)nNodes * 64;
    _Float16* Ph   = (_Float16*)(wsp + off);  off = align_up(off + nFeat * 2, 256);
    _Float16* Qh   = (_Float16*)(wsp + off);  off = align_up(off + nFeat * 2, 256);
    _Float16* B1h  = (_Float16*)(wsp + off);  off = align_up(off + nFeat * 2, 256);
    _Float16* B2h  = (_Float16*)(wsp + off);  off = align_up(off + nFeat * 2, 256);
    float*    gpart= (float*)(wsp + off);     off = align_up(off + (size_t)nGraphs * PPARTS * 132 * 4, 256);
    (void)ws_size;

    // ---- CSR build (vectorized scatter) + conv1 transform ----
    (void)hipMemsetAsync(cursor, 0, (size_t)nBuck * 8 * 4, stream);
    scatter_xform1_kernel<<<nCntB + XF1B, 256, 0, stream>>>(
        srcI, dstI, cursor, pairW, E, nNodes, nBuck, nCntB, x, W1, b1, Ph, Qh);
    bucket_sort_kernel<<<nBuck, 256, 0, stream>>>(pairW, cursor, rowInfo,
                                                  sortedSrc, nNodes);

    // ---- conv1 edge+agg ----
    edge_agg_mfma_kernel<<<2048, 256, 0, stream>>>(Ph, Qh, rowInfo, sortedSrc,
                                                   W2, b2, B1h, nNodes);
    // ---- conv2 ----
    node_xform2_kernel<<<2048, 256, 0, stream>>>(B1h, W3, b3, Ph, Qh, nNodes);
    edge_agg_mfma_kernel<<<2048, 256, 0, stream>>>(Ph, Qh, rowInfo, sortedSrc,
                                                   W4, b4, B2h, nNodes);

    // ---- pooling + classifier head ----
    pool_kernel<<<nGraphs * PPARTS, 256, 0, stream>>>(B2h, batch, gpart, nNodes);
    cls_kernel<<<nGraphs, 64, 0, stream>>>(gpart, Wc1, bc1, Wc2, bc2, out);
}

// Round 18
// 268.402 us; speedup vs baseline: 1.1204x; 1.0005x over previous
//
#include <hip/hip_runtime.h>
#include <hip/hip_bf16.h>

#define SLOPE 0.2f
#define NPB 64            // nodes per sort bucket
#define CAP 2048          // sortedSrc slots per bucket (mean 1638, 10 sigma)
#define SUBCAP 384        // pairW slots per (bucket, blockgroup) window
#define MAXBUCK 1024
#define EPB 4096          // edges per scatter chunk
#define XF1B 512          // xform1 blocks (merged launch)
#define PPARTS 16         // pool partials per graph

typedef _Float16 f16x8  __attribute__((ext_vector_type(8)));
typedef float    f32x4  __attribute__((ext_vector_type(4)));
typedef unsigned u32;
typedef unsigned u32x4  __attribute__((ext_vector_type(4)));

__device__ __forceinline__ float lrelu(float v) { return fmaxf(v, SLOPE * v); }

__device__ __forceinline__ float lane_bcast(float v, int k) {
    return __int_as_float(__builtin_amdgcn_readlane(__float_as_int(v), k));
}

// packed f16 leaky-relu: max(v, 0.2*v) elementwise
__device__ __forceinline__ f16x8 lrelu8(f16x8 v) {
    f16x8 s = v * (_Float16)SLOPE;
#if __has_builtin(__builtin_elementwise_max)
    return __builtin_elementwise_max(v, s);
#else
    f16x8 r;
#pragma unroll
    for (int i = 0; i < 8; ++i) r[i] = v[i] > s[i] ? v[i] : s[i];
    return r;
#endif
}

// f32 -> (hi, lo) f16 split; hi+lo reproduces v to ~2^-22.
__device__ __forceinline__ void split_f16(float v, _Float16& h, _Float16& l) {
    h = (_Float16)v;
    l = (_Float16)(v - (float)h);
}
__device__ __forceinline__ u32 pack_f16(_Float16 a, _Float16 b) {
    return (u32)__builtin_bit_cast(unsigned short, a) |
           ((u32)__builtin_bit_cast(unsigned short, b) << 16);
}

// ---------------------------------------------------------------------------
// Merged launch: blocks [0,nCntB) counting-sort a 4096-edge chunk into 8-way
// sub-cursor bucket windows of pairW. Histogram phase uses 4 wave-privatized
// LDS copies (R16: 299K bank-conflict cycles with one shared copy).
// Blocks [nCntB,..): conv1 node transform (f16 out).
// ---------------------------------------------------------------------------
__global__ void __launch_bounds__(256) scatter_xform1_kernel(
    const int* __restrict__ srcI, const int* __restrict__ dstI,
    int* __restrict__ cursor, u32* __restrict__ pairW,
    int E, int nNodes, int nBuck, int nCntB,
    const float* __restrict__ x,
    const float* __restrict__ W1, const float* __restrict__ b1,
    _Float16* __restrict__ Ph, _Float16* __restrict__ Qh)
{
    if (blockIdx.x < nCntB) {
        __shared__ int cnt4[4][MAXBUCK];     // wave-privatized histogram
        __shared__ int base[MAXBUCK];
        const int tid = threadIdx.x;
        const int wv  = tid >> 6;
        const int j   = blockIdx.x & 7;      // sub-cursor group (~XCD)
        const int e0 = blockIdx.x * EPB;
        const int e1 = min(e0 + EPB, E);
        const int n4 = (e1 - e0) >> 2;       // vectorizable quads
        const int4* d4 = (const int4*)(dstI + e0);
        const int4* s4 = (const int4*)(srcI + e0);

        for (int b = tid; b < nBuck; b += 256) {
            cnt4[0][b] = 0; cnt4[1][b] = 0; cnt4[2][b] = 0; cnt4[3][b] = 0;
        }
        __syncthreads();
        int* mycnt = cnt4[wv];
        for (int i = tid; i < n4; i += 256) {
            const int4 d = d4[i];
            atomicAdd(&mycnt[d.x >> 6], 1);
            atomicAdd(&mycnt[d.y >> 6], 1);
            atomicAdd(&mycnt[d.z >> 6], 1);
            atomicAdd(&mycnt[d.w >> 6], 1);
        }
        for (int e = e0 + (n4 << 2) + tid; e < e1; e += 256)   // tail
            atomicAdd(&mycnt[dstI[e] >> 6], 1);
        __syncthreads();
        for (int b = tid; b < nBuck; b += 256) {
            const int c = (cnt4[0][b] + cnt4[1][b]) + (cnt4[2][b] + cnt4[3][b]);
            base[b] = (c > 0)
                ? ((b * 8 + j) * SUBCAP + min(atomicAdd(&cursor[b * 8 + j], c), SUBCAP))
                : 0;
        }
        __syncthreads();
        for (int b = tid; b < nBuck; b += 256) cnt4[0][b] = 0;
        __syncthreads();
        int* scnt = cnt4[0];
        for (int i = tid; i < n4; i += 256) {
            const int4 d = d4[i];
            const int4 s = s4[i];
            {
                const int b = d.x >> 6;
                const int loc = atomicAdd(&scnt[b], 1);
                pairW[min(base[b] + loc, (b * 8 + j + 1) * SUBCAP - 1)] =
                    ((u32)s.x << 6) | (u32)(d.x & (NPB - 1));
            }
            {
                const int b = d.y >> 6;
                const int loc = atomicAdd(&scnt[b], 1);
                pairW[min(base[b] + loc, (b * 8 + j + 1) * SUBCAP - 1)] =
                    ((u32)s.y << 6) | (u32)(d.y & (NPB - 1));
            }
            {
                const int b = d.z >> 6;
                const int loc = atomicAdd(&scnt[b], 1);
                pairW[min(base[b] + loc, (b * 8 + j + 1) * SUBCAP - 1)] =
                    ((u32)s.z << 6) | (u32)(d.z & (NPB - 1));
            }
            {
                const int b = d.w >> 6;
                const int loc = atomicAdd(&scnt[b], 1);
                pairW[min(base[b] + loc, (b * 8 + j + 1) * SUBCAP - 1)] =
                    ((u32)s.w << 6) | (u32)(d.w & (NPB - 1));
            }
        }
        for (int e = e0 + (n4 << 2) + tid; e < e1; e += 256) { // tail
            const int d = dstI[e];
            const int b = d >> 6;
            const int loc = atomicAdd(&scnt[b], 1);
            pairW[min(base[b] + loc, (b * 8 + j + 1) * SUBCAP - 1)] =
                ((u32)srcI[e] << 6) | (u32)(d & (NPB - 1));
        }
        return;
    }
    const int lane = threadIdx.x & 63;
    const int wave = ((blockIdx.x - nCntB) * 256 + threadIdx.x) >> 6;
    const int nw   = (XF1B * 256) >> 6;

    float wd[6], wb[6];
#pragma unroll
    for (int r = 0; r < 6; ++r) {
        wb[r] = W1[(6 + r) * 64 + lane];
        wd[r] = W1[r * 64 + lane] - wb[r];
    }
    const float bb = b1[lane];
    for (int i = wave; i < nNodes; i += nw) {
        const float* xr = x + (size_t)i * 6;
        float p = bb, q = 0.f;
#pragma unroll
        for (int r = 0; r < 6; ++r) {
            float xv = xr[r];
            p = fmaf(xv, wd[r], p);
            q = fmaf(xv, wb[r], q);
        }
        Ph[(size_t)i * 64 + lane] = (_Float16)p;
        Qh[(size_t)i * 64 + lane] = (_Float16)q;
    }
}

// One block per bucket: compact the 8 sub-windows into LDS once (u32x4
// global loads), then count + scatter passes run entirely LDS->LDS.
__global__ void __launch_bounds__(256) bucket_sort_kernel(
    const u32* __restrict__ pairW, const int* __restrict__ cursor,
    int2* __restrict__ rowInfo, int* __restrict__ sortedSrc, int nNodes)
{
    __shared__ u32 pairLds[CAP];
    __shared__ int nodeCnt[NPB];
    __shared__ int nodeCur[NPB];
    __shared__ int wcS[8];
    __shared__ int wBase[9];
    const int b   = blockIdx.x;
    const int n0  = b * NPB;
    const int n1  = min(n0 + NPB, nNodes);
    const int tid = threadIdx.x;

    if (tid < NPB) nodeCnt[tid] = 0;
    if (tid < 8) wcS[tid] = min(cursor[b * 8 + tid], SUBCAP);
    __syncthreads();
    if (tid == 0) {
        int acc = 0;
#pragma unroll
        for (int jj = 0; jj < 8; ++jj) { wBase[jj] = acc; acc += wcS[jj]; }
        wBase[8] = acc;
    }
    __syncthreads();

    // compact sub-windows into pairLds (vector global loads, LDS stores)
#pragma unroll
    for (int jj = 0; jj < 8; ++jj) {
        const int w0 = (b * 8 + jj) * SUBCAP;
        const int wc = wcS[jj];
        const int d0 = wBase[jj];
        const int nv = wc >> 2;
        const u32x4* p4 = (const u32x4*)(pairW + w0);
        for (int i = tid; i < nv; i += 256) {
            const u32x4 v = p4[i];
            pairLds[d0 + i * 4 + 0] = v[0];
            pairLds[d0 + i * 4 + 1] = v[1];
            pairLds[d0 + i * 4 + 2] = v[2];
            pairLds[d0 + i * 4 + 3] = v[3];
        }
        for (int i = (nv << 2) + tid; i < wc; i += 256)
            pairLds[d0 + i] = pairW[w0 + i];
    }
    __syncthreads();

    const int total = wBase[8];
    for (int i = tid; i < total; i += 256)           // LDS->LDS count
        atomicAdd(&nodeCnt[pairLds[i] & (NPB - 1)], 1);
    __syncthreads();
    if (tid < 64) {                       // wave 0: prefix scan of 64 counts
        const int c = nodeCnt[tid];
        int inc = c;
#pragma unroll
        for (int off = 1; off < 64; off <<= 1) {
            int t = __shfl_up(inc, off);
            if (tid >= off) inc += t;
        }
        const int st = b * CAP + inc - c; // exclusive, bucket-window-local
        nodeCur[tid] = st;
        if (tid < n1 - n0) rowInfo[n0 + tid] = make_int2(st, c);
    }
    __syncthreads();
    for (int i = tid; i < total; i += 256) {         // LDS read, global write
        const u32 w = pairLds[i];
        const int pos = atomicAdd(&nodeCur[w & (NPB - 1)], 1);
        sortedSrc[pos] = (int)(w >> 6);
    }
}

// ---------------------------------------------------------------------------
// Node transform for conv2 (f16 in/out, VALU readlane -- R13-proven):
//   P[i] = A_i @ (W3top - W3bot) + b3;  Q[j] = A_j @ W3bot
// ---------------------------------------------------------------------------
__global__ void __launch_bounds__(256) node_xform2_kernel(
    const _Float16* __restrict__ B1h,
    const float* __restrict__ W3, const float* __restrict__ b3,
    _Float16* __restrict__ Ph, _Float16* __restrict__ Qh, int nNodes)
{
    const int lane = threadIdx.x & 63;
    const int wave = (blockIdx.x * blockDim.x + threadIdx.x) >> 6;
    const int nw   = (gridDim.x * blockDim.x) >> 6;

    float wd[64], wb[64];
#pragma unroll
    for (int k = 0; k < 64; ++k) {
        wb[k] = W3[(64 + k) * 64 + lane];
        wd[k] = W3[k * 64 + lane] - wb[k];
    }
    const float bb = b3[lane];

    for (int i = wave; i < nNodes; i += nw) {
        const float a = (float)B1h[(size_t)i * 64 + lane];
        float p0 = bb, p1 = 0.f, p2 = 0.f, p3 = 0.f;
        float q0 = 0.f, q1 = 0.f, q2 = 0.f, q3 = 0.f;
#pragma unroll
        for (int k = 0; k < 64; k += 4) {
            float a0 = lane_bcast(a, k);
            float a1 = lane_bcast(a, k + 1);
            float a2 = lane_bcast(a, k + 2);
            float a3 = lane_bcast(a, k + 3);
            p0 = fmaf(a0, wd[k],     p0);  q0 = fmaf(a0, wb[k],     q0);
            p1 = fmaf(a1, wd[k + 1], p1);  q1 = fmaf(a1, wb[k + 1], q1);
            p2 = fmaf(a2, wd[k + 2], p2);  q2 = fmaf(a2, wb[k + 2], q2);
            p3 = fmaf(a3, wd[k + 3], p3);  q3 = fmaf(a3, wb[k + 3], q3);
        }
        Ph[(size_t)i * 64 + lane] = (_Float16)((p0 + p1) + (p2 + p3));
        Qh[(size_t)i * 64 + lane] = (_Float16)((q0 + q1) + (q2 + q3));
    }
}

// ---------------------------------------------------------------------------
// CSR MFMA edge+aggregate (f16), TWO ADJACENT nodes per wave: rowInfo pair is
// one int4 load; the pair's sortedSrc windows are contiguous (same bucket) ->
// coalesced index stream. Otherwise the R13/R15-proven structure (VGPR 60).
// Pad slots replicate edge deg-1 -> unmasked max fold. f16 output rows.
// Floor: FETCH ~48 MB = 8 XCDs x 6.4 MB Qh compulsory L2 misses.
// C/D layout: row=(lane>>4)*4+reg, col=lane&15 (m89-verified).
// ---------------------------------------------------------------------------
__global__ void __launch_bounds__(256) edge_agg_mfma_kernel(
    const _Float16* __restrict__ Ph, const _Float16* __restrict__ Qh,
    const int2* __restrict__ rowInfo, const int* __restrict__ sortedSrc,
    const float* __restrict__ W, const float* __restrict__ b,
    _Float16* __restrict__ outB, int nNodes)
{
    __shared__ u32x4 wlds[16][64];   // 16 KB: frag f (0-7 wh, 8-15 wl), per lane

    const int tid  = threadIdx.x;
    const int lane = tid & 63;
    const int cn   = lane & 15;   // A: edge slot; B/C: column
    const int q    = lane >> 4;   // quad
    const int wv   = tid >> 6;    // wave in block
    const int wave = (blockIdx.x * 256 + tid) >> 6;
    const int nw   = (gridDim.x * 256) >> 6;

    // cooperative weight-fragment init (frag f: isLo=f>=8, nt=(f&7)>>1, ks=f&1)
#pragma unroll
    for (int i = 0; i < 4; ++i) {
        const int f    = wv + i * 4;
        const int isLo = f >> 3;
        const int g    = f & 7;
        const int nt   = g >> 1;
        const int ks   = g & 1;
        u32x4 d;
#pragma unroll
        for (int p = 0; p < 4; ++p) {
            float w0 = W[(ks * 32 + q * 8 + 2 * p)     * 64 + nt * 16 + cn];
            float w1 = W[(ks * 32 + q * 8 + 2 * p + 1) * 64 + nt * 16 + cn];
            _Float16 h0, l0, h1, l1;
            split_f16(w0, h0, l0);
            split_f16(w1, h1, l1);
            d[p] = isLo ? pack_f16(l0, l1) : pack_f16(h0, h1);
        }
        wlds[f][lane] = d;
    }
    float bc[4];
#pragma unroll
    for (int nt = 0; nt < 4; ++nt) bc[nt] = b[nt * 16 + cn];
    __syncthreads();

    const u32 nClamp = (u32)(nNodes - 1);
    const int nPairs = (nNodes + 1) >> 1;

    for (int t = wave; t < nPairs; t += nw) {
        const int n1 = 2 * t;
        const int n2 = 2 * t + 1;
        const bool has2 = (n2 < nNodes);

        // adjacent pair: one 16B rowInfo load
        const int2 ri1 = rowInfo[n1];
        const int2 ri2 = has2 ? rowInfo[n2] : make_int2(ri1.x, 0);
        const int rs1  = __builtin_amdgcn_readfirstlane(ri1.x);
        const int deg1 = __builtin_amdgcn_readfirstlane(ri1.y);
        const int rs2  = __builtin_amdgcn_readfirstlane(ri2.x);
        const int deg2 = __builtin_amdgcn_readfirstlane(ri2.y);
        const int d1c = max(deg1, 1) - 1;
        const int d2c = max(deg2, 1) - 1;

        const f16x8* P1 = (const f16x8*)(Ph + (size_t)n1 * 64);
        const f16x8* P2 = (const f16x8*)(Ph + (size_t)(has2 ? n2 : n1) * 64);
        const f16x8 p1A = P1[q], p1B = P1[4 + q];
        const f16x8 p2A = P2[q], p2B = P2[4 + q];

        float m10 = -INFINITY, m11 = -INFINITY, m12 = -INFINITY, m13 = -INFINITY;
        float m20 = -INFINITY, m21 = -INFINITY, m22 = -INFINITY, m23 = -INFINITY;

        const int gmax = max(deg1, deg2);
        for (int g0 = 0; g0 < gmax; g0 += 32) {
            // ---- issue ALL loads (both nodes, both groups) ----
            u32 sA1 = (u32)sortedSrc[rs1 + min(g0 + cn,      d1c)];
            u32 sB1 = (u32)sortedSrc[rs1 + min(g0 + 16 + cn, d1c)];
            u32 sA2 = (u32)sortedSrc[rs2 + min(g0 + cn,      d2c)];
            u32 sB2 = (u32)sortedSrc[rs2 + min(g0 + 16 + cn, d2c)];
            sA1 = min(sA1, nClamp); sB1 = min(sB1, nClamp);   // poison guard
            sA2 = min(sA2, nClamp); sB2 = min(sB2, nClamp);
            const f16x8* QA1 = (const f16x8*)(Qh + (size_t)sA1 * 64);
            const f16x8* QB1 = (const f16x8*)(Qh + (size_t)sB1 * 64);
            const f16x8* QA2 = (const f16x8*)(Qh + (size_t)sA2 * 64);
            const f16x8* QB2 = (const f16x8*)(Qh + (size_t)sB2 * 64);
            const f16x8 qA1a = QA1[q], qA1b = QA1[4 + q];
            const f16x8 qB1a = QB1[q], qB1b = QB1[4 + q];
            const f16x8 qA2a = QA2[q], qA2b = QA2[4 + q];
            const f16x8 qB2a = QB2[q], qB2b = QB2[4 + q];

            // ---- node 1 compute (unmasked fold: pads duplicate edge deg-1) ----
            if (g0 < deg1) {
                const f16x8 A00 = lrelu8(p1A + qA1a);
                const f16x8 A01 = lrelu8(p1B + qA1b);
                const f16x8 A10 = lrelu8(p1A + qB1a);
                const f16x8 A11 = lrelu8(p1B + qB1b);
#pragma unroll
                for (int nt = 0; nt < 4; ++nt) {
                    const f16x8 wh0 = __builtin_bit_cast(f16x8, wlds[nt * 2][lane]);
                    const f16x8 wh1 = __builtin_bit_cast(f16x8, wlds[nt * 2 + 1][lane]);
                    const f16x8 wl0 = __builtin_bit_cast(f16x8, wlds[8 + nt * 2][lane]);
                    const f16x8 wl1 = __builtin_bit_cast(f16x8, wlds[8 + nt * 2 + 1][lane]);
                    f32x4 a; a[0] = a[1] = a[2] = a[3] = bc[nt];
                    a = __builtin_amdgcn_mfma_f32_16x16x32_f16(A00, wl0, a, 0, 0, 0);
                    a = __builtin_amdgcn_mfma_f32_16x16x32_f16(A00, wh0, a, 0, 0, 0);
                    a = __builtin_amdgcn_mfma_f32_16x16x32_f16(A01, wl1, a, 0, 0, 0);
                    a = __builtin_amdgcn_mfma_f32_16x16x32_f16(A01, wh1, a, 0, 0, 0);
                    f32x4 c; c[0] = c[1] = c[2] = c[3] = bc[nt];
                    c = __builtin_amdgcn_mfma_f32_16x16x32_f16(A10, wl0, c, 0, 0, 0);
                    c = __builtin_amdgcn_mfma_f32_16x16x32_f16(A10, wh0, c, 0, 0, 0);
                    c = __builtin_amdgcn_mfma_f32_16x16x32_f16(A11, wl1, c, 0, 0, 0);
                    c = __builtin_amdgcn_mfma_f32_16x16x32_f16(A11, wh1, c, 0, 0, 0);
                    float m = (nt == 0) ? m10 : (nt == 1) ? m11 : (nt == 2) ? m12 : m13;
                    m = fmaxf(m, fmaxf(fmaxf(a[0], a[1]), fmaxf(a[2], a[3])));
                    m = fmaxf(m, fmaxf(fmaxf(c[0], c[1]), fmaxf(c[2], c[3])));
                    if (nt == 0) m10 = m; else if (nt == 1) m11 = m;
                    else if (nt == 2) m12 = m; else m13 = m;
                }
            }
            // ---- node 2 compute ----
            if (g0 < deg2) {
                const f16x8 A00 = lrelu8(p2A + qA2a);
                const f16x8 A01 = lrelu8(p2B + qA2b);
                const f16x8 A10 = lrelu8(p2A + qB2a);
                const f16x8 A11 = lrelu8(p2B + qB2b);
#pragma unroll
                for (int nt = 0; nt < 4; ++nt) {
                    const f16x8 wh0 = __builtin_bit_cast(f16x8, wlds[nt * 2][lane]);
                    const f16x8 wh1 = __builtin_bit_cast(f16x8, wlds[nt * 2 + 1][lane]);
                    const f16x8 wl0 = __builtin_bit_cast(f16x8, wlds[8 + nt * 2][lane]);
                    const f16x8 wl1 = __builtin_bit_cast(f16x8, wlds[8 + nt * 2 + 1][lane]);
                    f32x4 a; a[0] = a[1] = a[2] = a[3] = bc[nt];
                    a = __builtin_amdgcn_mfma_f32_16x16x32_f16(A00, wl0, a, 0, 0, 0);
                    a = __builtin_amdgcn_mfma_f32_16x16x32_f16(A00, wh0, a, 0, 0, 0);
                    a = __builtin_amdgcn_mfma_f32_16x16x32_f16(A01, wl1, a, 0, 0, 0);
                    a = __builtin_amdgcn_mfma_f32_16x16x32_f16(A01, wh1, a, 0, 0, 0);
                    f32x4 c; c[0] = c[1] = c[2] = c[3] = bc[nt];
                    c = __builtin_amdgcn_mfma_f32_16x16x32_f16(A10, wl0, c, 0, 0, 0);
                    c = __builtin_amdgcn_mfma_f32_16x16x32_f16(A10, wh0, c, 0, 0, 0);
                    c = __builtin_amdgcn_mfma_f32_16x16x32_f16(A11, wl1, c, 0, 0, 0);
                    c = __builtin_amdgcn_mfma_f32_16x16x32_f16(A11, wh1, c, 0, 0, 0);
                    float m = (nt == 0) ? m20 : (nt == 1) ? m21 : (nt == 2) ? m22 : m23;
                    m = fmaxf(m, fmaxf(fmaxf(a[0], a[1]), fmaxf(a[2], a[3])));
                    m = fmaxf(m, fmaxf(fmaxf(c[0], c[1]), fmaxf(c[2], c[3])));
                    if (nt == 0) m20 = m; else if (nt == 1) m21 = m;
                    else if (nt == 2) m22 = m; else m23 = m;
                }
            }
        }

        // cross-quad max butterflies + stores (f16)
        m10 = fmaxf(m10, __shfl_xor(m10, 16)); m10 = fmaxf(m10, __shfl_xor(m10, 32));
        m11 = fmaxf(m11, __shfl_xor(m11, 16)); m11 = fmaxf(m11, __shfl_xor(m11, 32));
        m12 = fmaxf(m12, __shfl_xor(m12, 16)); m12 = fmaxf(m12, __shfl_xor(m12, 32));
        m13 = fmaxf(m13, __shfl_xor(m13, 16)); m13 = fmaxf(m13, __shfl_xor(m13, 32));
        float sel1 = (q < 2) ? ((q == 0) ? m10 : m11) : ((q == 2) ? m12 : m13);
        outB[(size_t)n1 * 64 + q * 16 + cn] =
            (_Float16)((deg1 > 0) ? lrelu(sel1) : 0.0f);

        if (has2) {
            m20 = fmaxf(m20, __shfl_xor(m20, 16)); m20 = fmaxf(m20, __shfl_xor(m20, 32));
            m21 = fmaxf(m21, __shfl_xor(m21, 16)); m21 = fmaxf(m21, __shfl_xor(m21, 32));
            m22 = fmaxf(m22, __shfl_xor(m22, 16)); m22 = fmaxf(m22, __shfl_xor(m22, 32));
            m23 = fmaxf(m23, __shfl_xor(m23, 16)); m23 = fmaxf(m23, __shfl_xor(m23, 32));
            float sel2 = (q < 2) ? ((q == 0) ? m20 : m21) : ((q == 2) ? m22 : m23);
            outB[(size_t)n2 * 64 + q * 16 + cn] =
                (_Float16)((deg2 > 0) ? lrelu(sel2) : 0.0f);
        }
    }
}

__device__ __forceinline__ int lower_bound_i(const int* __restrict__ a, int n, int key)
{
    int lo = 0, hi = n;
    while (lo < hi) {
        int mid = (lo + hi) >> 1;
        if (a[mid] < key) lo = mid + 1; else hi = mid;
    }
    return lo;
}

// PPARTS blocks per graph (1024 blocks, streaming-BW bound), f16 input.
__global__ void __launch_bounds__(256) pool_kernel(
    const _Float16* __restrict__ Bh, const int* __restrict__ batch,
    float* __restrict__ gpart, int nNodes)
{
    const int gid  = blockIdx.x / PPARTS;
    const int part = blockIdx.x % PPARTS;
    const int c    = threadIdx.x & 63;
    const int wid  = threadIdx.x >> 6;

    const int s = lower_bound_i(batch, nNodes, gid);
    const int e = lower_bound_i(batch, nNodes, gid + 1);
    const int len = e - s;
    const int ps = s + (len * part) / PPARTS;
    const int pe = s + (len * (part + 1)) / PPARTS;

    float sum = 0.f, mx = -INFINITY;
    for (int n = ps + wid; n < pe; n += 4) {
        float v = (float)Bh[(size_t)n * 64 + c];
        sum += v;
        mx = fmaxf(mx, v);
    }
    __shared__ float ssum[4][64];
    __shared__ float smax[4][64];
    ssum[wid][c] = sum;
    smax[wid][c] = mx;
    __syncthreads();
    if (wid == 0) {
        sum = (ssum[0][c] + ssum[1][c]) + (ssum[2][c] + ssum[3][c]);
        mx  = fmaxf(fmaxf(smax[0][c], smax[1][c]), fmaxf(smax[2][c], smax[3][c]));
        float* row = gpart + (size_t)blockIdx.x * 132;
        row[c]      = sum;
        row[64 + c] = mx;
        if (c == 0) row[128] = (float)(pe - ps);
    }
}

// One wave per graph: combine PPARTS pool partials, then classifier head.
__global__ void __launch_bounds__(64) cls_kernel(
    const float* __restrict__ gpart,
    const float* __restrict__ Wc1, const float* __restrict__ bc1,
    const float* __restrict__ Wc2, const float* __restrict__ bc2,
    float* __restrict__ out)
{
    __shared__ float g[128];
    const int gid = blockIdx.x;
    const int c   = threadIdx.x;

    float s = 0.f, m = -INFINITY, cnt = 0.f;
#pragma unroll
    for (int p = 0; p < PPARTS; ++p) {
        const float* row = gpart + (size_t)(gid * PPARTS + p) * 132;
        s += row[c];
        m = fmaxf(m, row[64 + c]);
        cnt += row[128];
    }
    g[c]      = s / fmaxf(cnt, 1.0f);
    g[64 + c] = (cnt > 0.f) ? m : 0.0f;
    __syncthreads();

    float t = bc1[c];
#pragma unroll 8
    for (int k = 0; k < 128; ++k) t = fmaf(g[k], Wc1[k * 64 + c], t);
    t = lrelu(t);
    float p = t * Wc2[c];
#pragma unroll
    for (int off = 32; off > 0; off >>= 1) p += __shfl_down(p, off);
    if (c == 0) out[gid] = p + bc2[0];
}

static inline size_t align_up(size_t v, size_t a) { return (v + a - 1) & ~(a - 1); }

extern "C" void kernel_launch(void* const* d_in, const int* in_sizes, int n_in,
                              void* d_out, int out_size, void* d_ws, size_t ws_size,
                              hipStream_t stream)
{
    const float* x     = (const float*)d_in[0];
    const int*   ei    = (const int*)d_in[1];
    const int*   batch = (const int*)d_in[2];
    const float* W1  = (const float*)d_in[3];
    const float* b1  = (const float*)d_in[4];
    const float* W2  = (const float*)d_in[5];
    const float* b2  = (const float*)d_in[6];
    const float* W3  = (const float*)d_in[7];
    const float* b3  = (const float*)d_in[8];
    const float* W4  = (const float*)d_in[9];
    const float* b4  = (const float*)d_in[10];
    const float* Wc1 = (const float*)d_in[11];
    const float* bc1 = (const float*)d_in[12];
    const float* Wc2 = (const float*)d_in[13];
    const float* bc2 = (const float*)d_in[14];
    float* out = (float*)d_out;

    const int nNodes  = in_sizes[0] / 6;
    const int E       = in_sizes[1] / 2;
    const int nGraphs = out_size;
    const int* srcI = ei;
    const int* dstI = ei + E;
    const int nBuck = (nNodes + NPB - 1) / NPB;
    const int nCntB = (E + EPB - 1) / EPB;

    // workspace carve-up (256B-aligned)
    char* wsp = (char*)d_ws;
    size_t off = 0;
    int*  cursor    = (int*)(wsp + off);   off = align_up(off + (size_t)MAXBUCK * 8 * 4, 256);
    int2* rowInfo   = (int2*)(wsp + off);  off = align_up(off + (size_t)nNodes * 8, 256);
    int*  sortedSrc = (int*)(wsp + off);   off = align_up(off + (size_t)nBuck * CAP * 4, 256);
    u32*  pairW     = (u32*)(wsp + off);   off = align_up(off + (size_t)nBuck * 8 * SUBCAP * 4, 256);
    const size_t nFeat = (size_t)nNodes * 64;
    _Float16* Ph   = (_Float16*)(wsp + off);  off = align_up(off + nFeat * 2, 256);
    _Float16* Qh   = (_Float16*)(wsp + off);  off = align_up(off + nFeat * 2, 256);
    _Float16* B1h  = (_Float16*)(wsp + off);  off = align_up(off + nFeat * 2, 256);
    _Float16* B2h  = (_Float16*)(wsp + off);  off = align_up(off + nFeat * 2, 256);
    float*    gpart= (float*)(wsp + off);     off = align_up(off + (size_t)nGraphs * PPARTS * 132 * 4, 256);
    (void)ws_size;

    // ---- CSR build (vectorized scatter, privatized hist) + conv1 transform ----
    (void)hipMemsetAsync(cursor, 0, (size_t)nBuck * 8 * 4, stream);
    scatter_xform1_kernel<<<nCntB + XF1B, 256, 0, stream>>>(
        srcI, dstI, cursor, pairW, E, nNodes, nBuck, nCntB, x, W1, b1, Ph, Qh);
    bucket_sort_kernel<<<nBuck, 256, 0, stream>>>(pairW, cursor, rowInfo,
                                                  sortedSrc, nNodes);

    // ---- conv1 edge+agg ----
    edge_agg_mfma_kernel<<<2048, 256, 0, stream>>>(Ph, Qh, rowInfo, sortedSrc,
                                                   W2, b2, B1h, nNodes);
    // ---- conv2 ----
    node_xform2_kernel<<<2048, 256, 0, stream>>>(B1h, W3, b3, Ph, Qh, nNodes);
    edge_agg_mfma_kernel<<<2048, 256, 0, stream>>>(Ph, Qh, rowInfo, sortedSrc,
                                                   W4, b4, B2h, nNodes);

    // ---- pooling + classifier head ----
    pool_kernel<<<nGraphs * PPARTS, 256, 0, stream>>>(B2h, batch, gpart, nNodes);
    cls_kernel<<<nGraphs, 64, 0, stream>>>(gpart, Wc1, bc1, Wc2, bc2, out);
}